// Round 1
// baseline (146.617 us; speedup 1.0000x reference)
//
#include <hip/hip_runtime.h>
#include <math.h>

// FilterBankConstructorND: K spheres of dim D+2=5, D=3, M=4 tetra rotations.
//   p = normalize(spheres[k,:3] / (spheres[k,4]+eps)); q = normalize(ones_vec)
//   u = p+q;  a = 2/||u||^2;  w = q - a*(q.u)*u
//   R0 = I - a*u*u^T - 2*q*w^T          (two Householders composed; R0 @ p = q)
//   r = R0 @ s_top;  for m: f = R0^T @ (T_m @ r);  fb[m] = (f0,f1,f2,s3,s4)
// Output: concat( R0 (K*9 floats), filter_banks (K*M*5 floats) )
//
// Memory-bound: ~20 MB read + ~121.6 MB write => ~22 us kernel roofline.
// Evidence from R0 rocprof: top-5 dispatches are all harness poison fills
// (~71 us each, 486 MB @ 6.8 TB/s); fbank_kernel < 70.9 us (absent from
// top-5). dur_us = poison + tiny resets + kernel.
//
// v6: fb staged as 5 aligned vf4/sphere -> flush is pure ds_read_b128 +
// coalesced nontemporal vf4 stores, ZERO per-element index math (v5 did
// ~5K scattered ds_read_b32 + ~10K VALU div/mod per block). Input staging
// via global_load_lds DMA (no VGPR round-trip). tetra/ones via uniform
// scalar loads (sT staging dropped). LDS 29.7 KB -> still 5 blocks/CU.
// Disambiguates: flush-bound (expect -15..-30us) vs kernel-at-roofline
// (expect null => harness-dominated => ROOFLINE).

typedef float vf4 __attribute__((ext_vector_type(4)));

__global__ __launch_bounds__(256) void fbank_kernel(
    const float* __restrict__ spheres,
    const float* __restrict__ ones_vec,
    const float* __restrict__ tetra,
    float* __restrict__ out,
    int K)
{
    __shared__ __align__(16) float rot_s[256 * 9];  //  9216 B; stride-9 (odd) b32 writes: <=2-way, free
    __shared__ __align__(16) vf4   fb_s[256 * 5];   // 20480 B; first 320 slots union the input stage

    const int tid = threadIdx.x;
    const size_t base  = (size_t)blockIdx.x * 1280;   // floats
    const size_t total = (size_t)K * 5;
    const bool full = (base + 1280 <= total);         // wave-uniform (always true for K=1M)

    // ---- stage inputs: 256 spheres = 1280 floats = 320 vf4, DMA direct to LDS
    if (full) {
        __builtin_amdgcn_global_load_lds((const unsigned int*)(spheres + base) + tid * 4,
                                         (unsigned int*)fb_s + tid * 4, 16, 0, 0);
        if (tid < 64)
            __builtin_amdgcn_global_load_lds((const unsigned int*)(spheres + base) + 1024 + tid * 4,
                                             (unsigned int*)fb_s + 1024 + tid * 4, 16, 0, 0);
    } else {
        const vf4* spv = (const vf4*)(spheres + base);
        for (int i = tid; i < 320; i += 256)
            if (base + (size_t)i * 4 + 4 <= total)
                fb_s[i] = spv[i];
    }
    __syncthreads();   // drains vmcnt (compiler emits full waitcnt before s_barrier)

    // read my sphere into registers (stride-5 b32: odd stride -> 2-way, free)
    const float* inS = (const float*)fb_s;
    const float s0 = inS[tid * 5 + 0], s1 = inS[tid * 5 + 1], s2 = inS[tid * 5 + 2];
    const float s3 = inS[tid * 5 + 3], s4 = inS[tid * 5 + 4];
    __syncthreads();   // all input reads complete before fb_s is overwritten

    // unembed + normalize center (1-ulp rcp/rsq: error << 0.113 threshold)
    const float inv = __builtin_amdgcn_rcpf(s4 + 1e-12f);
    const float c0 = s0 * inv, c1 = s1 * inv, c2 = s2 * inv;
    const float rn = __builtin_amdgcn_rsqf(c0 * c0 + c1 * c1 + c2 * c2);
    const float p0 = c0 * rn, p1 = c1 * rn, p2 = c2 * rn;

    // normalized ones vector (uniform -> scalar loads, K$-cached)
    float o0 = ones_vec[0], o1 = ones_vec[1], o2 = ones_vec[2];
    const float orn = __builtin_amdgcn_rsqf(o0 * o0 + o1 * o1 + o2 * o2);
    o0 *= orn; o1 *= orn; o2 *= orn;

    // R0 = I - a*u*u^T - 2*q*w^T
    const float u0 = p0 + o0, u1 = p1 + o1, u2 = p2 + o2;
    const float a  = 2.0f * __builtin_amdgcn_rcpf(u0 * u0 + u1 * u1 + u2 * u2);
    const float atq = a * (o0 * u0 + o1 * u1 + o2 * u2);
    const float w0 = o0 - atq * u0, w1 = o1 - atq * u1, w2 = o2 - atq * u2;

    const float uu[3] = {u0, u1, u2}, oo[3] = {o0, o1, o2}, ww[3] = {w0, w1, w2};
    float R[3][3];
#pragma unroll
    for (int i = 0; i < 3; ++i)
#pragma unroll
        for (int j = 0; j < 3; ++j)
            R[i][j] = ((i == j) ? 1.0f : 0.0f) - a * uu[i] * uu[j] - 2.0f * oo[i] * ww[j];

    // stage R early (rot_s not unioned; only needs my registers)
#pragma unroll
    for (int i = 0; i < 3; ++i)
#pragma unroll
        for (int j = 0; j < 3; ++j)
            rot_s[tid * 9 + i * 3 + j] = R[i][j];

    // r = R0 @ s_top; filter banks f = R0^T @ (T_m @ r) -> registers
    const float r0 = R[0][0] * s0 + R[0][1] * s1 + R[0][2] * s2;
    const float r1 = R[1][0] * s0 + R[1][1] * s1 + R[1][2] * s2;
    const float r2 = R[2][0] * s0 + R[2][1] * s1 + R[2][2] * s2;

    float f[12];
#pragma unroll
    for (int m = 0; m < 4; ++m) {
        const float* T = tetra + m * 9;     // uniform addr -> s_load, cached
        const float g0 = T[0] * r0 + T[1] * r1 + T[2] * r2;
        const float g1 = T[3] * r0 + T[4] * r1 + T[5] * r2;
        const float g2 = T[6] * r0 + T[7] * r1 + T[8] * r2;
        f[m * 3 + 0] = R[0][0] * g0 + R[1][0] * g1 + R[2][0] * g2;
        f[m * 3 + 1] = R[0][1] * g0 + R[1][1] * g1 + R[2][1] * g2;
        f[m * 3 + 2] = R[0][2] * g0 + R[1][2] * g1 + R[2][2] * g2;
    }

    // pack 20 output floats of my sphere into 5 aligned vf4 (ds_write_b128 x5)
    {
        vf4 v0, v1, v2, v3, v4;
        v0.x = f[0];  v0.y = f[1];  v0.z = f[2];  v0.w = s3;
        v1.x = s4;    v1.y = f[3];  v1.z = f[4];  v1.w = f[5];
        v2.x = s3;    v2.y = s4;    v2.z = f[6];  v2.w = f[7];
        v3.x = f[8];  v3.y = s3;    v3.z = s4;    v3.w = f[9];
        v4.x = f[10]; v4.y = f[11]; v4.z = s3;    v4.w = s4;
        fb_s[tid * 5 + 0] = v0;
        fb_s[tid * 5 + 1] = v1;
        fb_s[tid * 5 + 2] = v2;
        fb_s[tid * 5 + 3] = v3;
        fb_s[tid * 5 + 4] = v4;
    }
    __syncthreads();

    // ---- flush: 576 rot vf4 + 1280 fb vf4, lane-linear ds_read_b128,
    //      coalesced nontemporal stores, zero index math
    float* rot_out = out + (size_t)blockIdx.x * 2304;
    float* fb_out  = out + (size_t)K * 9 + (size_t)blockIdx.x * 5120;
    if (full) {
        vf4* ro = (vf4*)rot_out;
        const vf4* rs = (const vf4*)rot_s;
        __builtin_nontemporal_store(rs[tid],       &ro[tid]);
        __builtin_nontemporal_store(rs[256 + tid], &ro[256 + tid]);
        if (tid < 64)
            __builtin_nontemporal_store(rs[512 + tid], &ro[512 + tid]);
        vf4* fo = (vf4*)fb_out;
#pragma unroll
        for (int j = 0; j < 5; ++j)
            __builtin_nontemporal_store(fb_s[j * 256 + tid], &fo[j * 256 + tid]);
    } else {
        const long long limr = (long long)K * 9 - (long long)blockIdx.x * 2304;
        for (int i = tid; i < 576; i += 256)
            if ((long long)i * 4 + 3 < limr)
                *(vf4*)(rot_out + (size_t)i * 4) = *(const vf4*)&rot_s[i * 4];
        const long long limf = (long long)K * 20 - (long long)blockIdx.x * 5120;
        for (int i = tid; i < 1280; i += 256)
            if ((long long)i * 4 + 3 < limf)
                *(vf4*)(fb_out + (size_t)i * 4) = fb_s[i];
    }
}

extern "C" void kernel_launch(void* const* d_in, const int* in_sizes, int n_in,
                              void* d_out, int out_size, void* d_ws, size_t ws_size,
                              hipStream_t stream) {
    const float* spheres  = (const float*)d_in[0];   // (K, 5)
    const float* ones_vec = (const float*)d_in[1];   // (3,)
    const float* tetra    = (const float*)d_in[2];   // (4, 3, 3)
    float* out = (float*)d_out;                      // K*9 rot, then K*4*5 fb
    const int K = in_sizes[0] / 5;
    const int grid = (K + 255) / 256;
    fbank_kernel<<<grid, 256, 0, stream>>>(spheres, ones_vec, tetra, out, K);
}